// Round 1
// baseline (209.582 us; speedup 1.0000x reference)
//
#include <hip/hip_runtime.h>
#include <math.h>

// ---- Problem constants -----------------------------------------------------
#define NQ        12
#define NSTATES   4096           // 2^12
#define PATCH_PIX 256            // 16x16
#define NPS       14
#define NPATCH    196            // 14*14
#define NB        4
#define NGATES    20             // gates per circuit layer (pidx == gate index)
#define NPPL_C    32             // param stride per layer
#define NCLS      1000
#define FEATDIM   2352           // 196*12
#define SCALE_F   0.28867513459481287f  // 1/sqrt(12)

// Butterfly gate qubit pairs (i1 < i2), pidx == g for g in [0,20)
__device__ const int GQA[NGATES] = {0,2,4,6,8,10, 0,1,4,5,8,9, 0,1,2,3, 0,1,2,3};
__device__ const int GQB[NGATES] = {1,3,5,7,9,11, 2,3,6,7,10,11, 4,5,6,7, 8,9,10,11};

// ---- Kernel 1: channel mean + patchify + projection ------------------------
// grid (196, 4), block 256. One block per (patch, batch); thread = pixel.
__global__ __launch_bounds__(256) void proj_kernel(
    const float* __restrict__ x,      // (4,3,224,224)
    const float* __restrict__ Wp,     // (12,256)
    const float* __restrict__ bproj,  // (12,)
    float* __restrict__ feats)        // (784,12)
{
    int tid = threadIdx.x;
    int p = blockIdx.x, b = blockIdx.y;
    int py = p / NPS, px = p % NPS;
    int r = tid >> 4, cc = tid & 15;
    int row = py * 16 + r, col = px * 16 + cc;
    const float* xb = x + (size_t)b * 3 * 224 * 224;
    int off = row * 224 + col;
    float pix = (xb[off] + xb[224*224 + off] + xb[2*224*224 + off]) * (1.0f/3.0f);

    float part[NQ];
    #pragma unroll
    for (int q = 0; q < NQ; q++) part[q] = pix * Wp[q * PATCH_PIX + tid];

    // block reduce 12 values over 256 threads
    #pragma unroll
    for (int q = 0; q < NQ; q++) {
        #pragma unroll
        for (int o = 32; o > 0; o >>= 1) part[q] += __shfl_down(part[q], o);
    }
    __shared__ float red[4][NQ];
    int lane = tid & 63, wv = tid >> 6;
    if (lane == 0) {
        #pragma unroll
        for (int q = 0; q < NQ; q++) red[wv][q] = part[q];
    }
    __syncthreads();
    if (tid < NQ) {
        float s = red[0][tid] + red[1][tid] + red[2][tid] + red[3][tid];
        feats[(b * NPATCH + p) * NQ + tid] = s + bproj[tid];
    }
}

// ---- Kernel 2: quantum circuit ---------------------------------------------
// grid (196, 4, 3), block 256. State (4096 fp32) in LDS; 40 RBS gates; <Z_q>.
__global__ __launch_bounds__(256) void qcirc_kernel(
    const float* __restrict__ feats,  // (784,12)
    const float* __restrict__ qp,
    const float* __restrict__ kp,
    const float* __restrict__ vp,
    float* __restrict__ qkv)          // (3,784,12)
{
    __shared__ float st[NSTATES];
    __shared__ float ch[NQ], sh[NQ];
    __shared__ float p16[16];
    __shared__ float gc2[40], gs2[40], gcs[40];
    __shared__ float red[4][NQ];

    int tid = threadIdx.x;
    int p = blockIdx.x, b = blockIdx.y, c = blockIdx.z;
    int bp = b * NPATCH + p;
    const float* params = (c == 0) ? qp : (c == 1) ? kp : vp;

    if (tid < NQ) {
        float h = 0.5f * feats[bp * NQ + tid];
        ch[tid] = cosf(h);
        sh[tid] = sinf(h);
    }
    if (tid < 40) {
        int l = tid / NGATES, g = tid % NGATES;
        float th = params[l * NPPL_C + g];
        float cth = cosf(th), sth = sinf(th);
        gc2[tid] = cth * cth; gs2[tid] = sth * sth; gcs[tid] = cth * sth;
    }
    __syncthreads();

    // product over qubits 0..3 (state bits 11..8) indexed by e in [0,16)
    if (tid < 16) {
        float v = 1.0f;
        #pragma unroll
        for (int q = 0; q < 4; q++) {
            int bit = (tid >> (3 - q)) & 1;
            v *= bit ? sh[q] : ch[q];
        }
        p16[tid] = v;
    }
    // product over qubits 4..11 (state bits 7..0) indexed by tid
    float hiprod = 1.0f;
    #pragma unroll
    for (int q = 4; q < NQ; q++) {
        int bit = (tid >> (11 - q)) & 1;
        hiprod *= bit ? sh[q] : ch[q];
    }
    __syncthreads();
    #pragma unroll
    for (int e = 0; e < 16; e++) st[e * 256 + tid] = p16[e] * hiprod;

    // 40 gates (2 circuit layers x 20 butterfly gates)
    for (int gg = 0; gg < 40; gg++) {
        __syncthreads();
        int g = (gg >= NGATES) ? gg - NGATES : gg;
        float c2 = gc2[gg], s2 = gs2[gg], cs = gcs[gg];
        int phi = 11 - GQA[g];            // higher bit position
        int plo = 11 - GQB[g];            // lower bit position
        int bhi = 1 << phi, blo = 1 << plo;
        #pragma unroll
        for (int k = 0; k < 4; k++) {
            int gidx = tid + 256 * k;     // group in [0,1024)
            int t = ((gidx >> plo) << (plo + 1)) | (gidx & (blo - 1));
            int base = ((t >> phi) << (phi + 1)) | (t & (bhi - 1));
            float a0 = st[base];
            float a1 = st[base + blo];
            float a2 = st[base + bhi];
            float a3 = st[base + bhi + blo];
            st[base]             =  c2 * a0 + s2 * a1 - cs * a2 + cs * a3;
            st[base + blo]       =  s2 * a0 + c2 * a1 + cs * a2 - cs * a3;
            st[base + bhi]       =  cs * a0 - cs * a1 + c2 * a2 + s2 * a3;
            st[base + bhi + blo] = -cs * a0 + cs * a1 + s2 * a2 + c2 * a3;
        }
    }
    __syncthreads();

    // expvals: <Z_q> = sum_idx sign_q(idx) * st[idx]^2
    float part[NQ];
    #pragma unroll
    for (int q = 0; q < NQ; q++) part[q] = 0.0f;
    #pragma unroll
    for (int e = 0; e < 16; e++) {
        int idx = e * 256 + tid;
        float v = st[idx];
        float pr = v * v;
        #pragma unroll
        for (int q = 0; q < NQ; q++)
            part[q] += ((idx >> (11 - q)) & 1) ? -pr : pr;
    }
    #pragma unroll
    for (int q = 0; q < NQ; q++) {
        #pragma unroll
        for (int o = 32; o > 0; o >>= 1) part[q] += __shfl_down(part[q], o);
    }
    int lane = tid & 63, wv = tid >> 6;
    if (lane == 0) {
        #pragma unroll
        for (int q = 0; q < NQ; q++) red[wv][q] = part[q];
    }
    __syncthreads();
    if (tid < NQ) {
        float s = red[0][tid] + red[1][tid] + red[2][tid] + red[3][tid];
        qkv[((size_t)c * (NB * NPATCH) + bp) * NQ + tid] = s;
    }
}

// ---- Kernel 3: attention ---------------------------------------------------
// grid (196, 4), block 256. Thread k handles key-patch k (k<196).
__global__ __launch_bounds__(256) void attn_kernel(
    const float* __restrict__ qkv,    // (3,784,12)
    float* __restrict__ outb)         // (4,196,12) == (4,2352)
{
    int tid = threadIdx.x;
    int qp = blockIdx.x, b = blockIdx.y;
    const float* Q = qkv;
    const float* K = qkv + NB * NPATCH * NQ;
    const float* V = qkv + 2 * NB * NPATCH * NQ;

    __shared__ float redm[4], reds[4], redv[4][NQ];

    float qv[NQ];
    #pragma unroll
    for (int d = 0; d < NQ; d++) qv[d] = Q[(b * NPATCH + qp) * NQ + d];

    float score = -1e30f;
    if (tid < NPATCH) {
        float s = 0.0f;
        #pragma unroll
        for (int d = 0; d < NQ; d++) s += qv[d] * K[(b * NPATCH + tid) * NQ + d];
        score = s * SCALE_F;
    }
    // block max
    float m = score;
    #pragma unroll
    for (int o = 32; o > 0; o >>= 1) m = fmaxf(m, __shfl_down(m, o));
    int lane = tid & 63, wv = tid >> 6;
    if (lane == 0) redm[wv] = m;
    __syncthreads();
    float maxv = fmaxf(fmaxf(redm[0], redm[1]), fmaxf(redm[2], redm[3]));

    float w = (tid < NPATCH) ? expf(score - maxv) : 0.0f;
    float sm = w;
    #pragma unroll
    for (int o = 32; o > 0; o >>= 1) sm += __shfl_down(sm, o);
    if (lane == 0) reds[wv] = sm;

    float part[NQ];
    #pragma unroll
    for (int d = 0; d < NQ; d++) part[d] = 0.0f;
    if (tid < NPATCH) {
        #pragma unroll
        for (int d = 0; d < NQ; d++) part[d] = w * V[(b * NPATCH + tid) * NQ + d];
    }
    #pragma unroll
    for (int d = 0; d < NQ; d++) {
        #pragma unroll
        for (int o = 32; o > 0; o >>= 1) part[d] += __shfl_down(part[d], o);
    }
    if (lane == 0) {
        #pragma unroll
        for (int d = 0; d < NQ; d++) redv[wv][d] = part[d];
    }
    __syncthreads();
    if (tid < NQ) {
        float sumv = reds[0] + reds[1] + reds[2] + reds[3];
        float s = redv[0][tid] + redv[1][tid] + redv[2][tid] + redv[3][tid];
        outb[(size_t)b * FEATDIM + qp * NQ + tid] = s / sumv;
    }
}

// ---- Kernel 4: classifier --------------------------------------------------
// grid 1000, block 256. Block o: logits[b][o] = out[b] . W_cls[o] + b_cls[o].
__global__ __launch_bounds__(256) void cls_kernel(
    const float* __restrict__ outb,   // (4,2352)
    const float* __restrict__ Wc,     // (1000,2352)
    const float* __restrict__ bc,     // (1000,)
    float* __restrict__ logits)       // (4,1000)
{
    int o = blockIdx.x, tid = threadIdx.x;
    float acc[NB] = {0.0f, 0.0f, 0.0f, 0.0f};
    const float* wrow = Wc + (size_t)o * FEATDIM;
    for (int j = tid; j < FEATDIM; j += 256) {
        float w = wrow[j];
        #pragma unroll
        for (int b = 0; b < NB; b++) acc[b] += w * outb[(size_t)b * FEATDIM + j];
    }
    #pragma unroll
    for (int b = 0; b < NB; b++) {
        #pragma unroll
        for (int off = 32; off > 0; off >>= 1) acc[b] += __shfl_down(acc[b], off);
    }
    __shared__ float red[4][NB];
    int lane = tid & 63, wv = tid >> 6;
    if (lane == 0) {
        #pragma unroll
        for (int b = 0; b < NB; b++) red[wv][b] = acc[b];
    }
    __syncthreads();
    if (tid < NB) {
        float s = red[0][tid] + red[1][tid] + red[2][tid] + red[3][tid];
        logits[(size_t)tid * NCLS + o] = s + bc[o];
    }
}

// ---- Launch ----------------------------------------------------------------
extern "C" void kernel_launch(void* const* d_in, const int* in_sizes, int n_in,
                              void* d_out, int out_size, void* d_ws, size_t ws_size,
                              hipStream_t stream) {
    const float* x     = (const float*)d_in[0];
    const float* Wp    = (const float*)d_in[1];
    const float* bproj = (const float*)d_in[2];
    const float* qp    = (const float*)d_in[3];
    const float* kp    = (const float*)d_in[4];
    const float* vp    = (const float*)d_in[5];
    const float* Wc    = (const float*)d_in[6];
    const float* bc    = (const float*)d_in[7];
    float* logits = (float*)d_out;

    float* ws    = (float*)d_ws;
    float* feats = ws;                       // 784*12      = 9408 floats
    float* qkv   = ws + 9408;                // 3*784*12    = 28224 floats
    float* outb  = ws + 9408 + 28224;        // 4*2352      = 9408 floats

    proj_kernel <<<dim3(NPATCH, NB),    256, 0, stream>>>(x, Wp, bproj, feats);
    qcirc_kernel<<<dim3(NPATCH, NB, 3), 256, 0, stream>>>(feats, qp, kp, vp, qkv);
    attn_kernel <<<dim3(NPATCH, NB),    256, 0, stream>>>(qkv, outb);
    cls_kernel  <<<NCLS,                256, 0, stream>>>(outb, Wc, bc, logits);
}

// Round 2
// 147.725 us; speedup vs baseline: 1.4187x; 1.4187x over previous
//
#include <hip/hip_runtime.h>
#include <math.h>

// ---- Problem constants -----------------------------------------------------
#define NQ        12
#define NSTATES   4096           // 2^12
#define PATCH_PIX 256            // 16x16
#define NPS       14
#define NPATCH    196            // 14*14
#define NB        4
#define NCLS      1000
#define FEATDIM   2352           // 196*12
#define SCALE_F   0.28867513459481287f  // 1/sqrt(12)

// ---- Kernel 1: channel mean + patchify + projection ------------------------
__global__ __launch_bounds__(256) void proj_kernel(
    const float* __restrict__ x,      // (4,3,224,224)
    const float* __restrict__ Wp,     // (12,256)
    const float* __restrict__ bproj,  // (12,)
    float* __restrict__ feats)        // (784,12)
{
    int tid = threadIdx.x;
    int p = blockIdx.x, b = blockIdx.y;
    int py = p / NPS, px = p % NPS;
    int r = tid >> 4, cc = tid & 15;
    int row = py * 16 + r, col = px * 16 + cc;
    const float* xb = x + (size_t)b * 3 * 224 * 224;
    int off = row * 224 + col;
    float pix = (xb[off] + xb[224*224 + off] + xb[2*224*224 + off]) * (1.0f/3.0f);

    float part[NQ];
    #pragma unroll
    for (int q = 0; q < NQ; q++) part[q] = pix * Wp[q * PATCH_PIX + tid];

    #pragma unroll
    for (int q = 0; q < NQ; q++) {
        #pragma unroll
        for (int o = 32; o > 0; o >>= 1) part[q] += __shfl_down(part[q], o);
    }
    __shared__ float red[4][NQ];
    int lane = tid & 63, wv = tid >> 6;
    if (lane == 0) {
        #pragma unroll
        for (int q = 0; q < NQ; q++) red[wv][q] = part[q];
    }
    __syncthreads();
    if (tid < NQ) {
        float s = red[0][tid] + red[1][tid] + red[2][tid] + red[3][tid];
        feats[(b * NPATCH + p) * NQ + tid] = s + bproj[tid];
    }
}

// ---- Quantum circuit: register-resident statevector ------------------------
// Each thread holds 16 amps (4 state bits in registers, 8 bits = tid).
// Gates within a "run" act on register bits only (pure VALU). Between runs the
// state is relaid out through LDS with an XOR bank swizzle.

__device__ __forceinline__ int swz(int i) { return i ^ ((i >> 5) & 31); }

// Place tid's 8 bits into the positions NOT in RM, descending (tid bit7 -> highest).
template<int RM>
__device__ __forceinline__ int spread_tid(int tid) {
    int idx = 0, tb = 7;
    #pragma unroll
    for (int pos = 11; pos >= 0; --pos) {
        if (!(RM & (1 << pos))) { idx |= ((tid >> tb) & 1) << pos; --tb; }
    }
    return idx;
}

// Place r's 4 bits into the positions in RM, descending (r bit3 -> highest).
template<int RM>
__device__ __forceinline__ int place_r(int r) {
    int idx = 0, rb = 3;
    #pragma unroll
    for (int pos = 11; pos >= 0; --pos) {
        if (RM & (1 << pos)) { idx |= ((r >> rb) & 1) << pos; --rb; }
    }
    return idx;
}

template<int RMA, int RMB>
__device__ __forceinline__ void relayout(float amp[16], float* lds, int tid) {
    int baseA = spread_tid<RMA>(tid);
    #pragma unroll
    for (int r = 0; r < 16; ++r) lds[swz(baseA | place_r<RMA>(r))] = amp[r];
    __syncthreads();
    int baseB = spread_tid<RMB>(tid);
    #pragma unroll
    for (int r = 0; r < 16; ++r) amp[r] = lds[swz(baseB | place_r<RMB>(r))];
    __syncthreads();
}

// RBS 4x4 on register bits MI (higher bit = qubit w1) and MJ (lower = w2).
// Symmetric form: out_u0 = c2*u0+s2*u1+cs*(v1-v0), out_u1 = s2*u0+c2*u1-cs*(v1-v0),
//                 out_v0 = c2*v0+s2*v1+cs*(u0-u1), out_v1 = s2*v0+c2*v1-cs*(u0-u1).
template<int MI, int MJ>
__device__ __forceinline__ void apply_gate(float amp[16], float c2, float s2, float cs) {
    #pragma unroll
    for (int m = 0; m < 16; ++m) {
        if (m & (MI | MJ)) continue;
        float a0 = amp[m], a1 = amp[m | MJ], a2 = amp[m | MI], a3 = amp[m | MI | MJ];
        float du = a0 - a1, dv = a3 - a2;
        amp[m]           = c2 * a0 + s2 * a1 + cs * dv;
        amp[m | MJ]      = s2 * a0 + c2 * a1 - cs * dv;
        amp[m | MI]      = c2 * a2 + s2 * a3 + cs * du;
        amp[m | MI | MJ] = s2 * a2 + c2 * a3 - cs * du;
    }
}

// Run layouts (register-bit masks). Qubit q <-> state bit (11-q).
// R1: q0-3, R2: q4-7, R3: q8-11, R4: q0,1,4,5, R5: q2,3,6,7, R6: q0,1,8,9, R7: q2,3,10,11
#define RM1 0xF00
#define RM2 0x0F0
#define RM3 0x00F
#define RM4 0xCC0
#define RM5 0x330
#define RM6 0xC0C
#define RM7 0x303

__global__ __launch_bounds__(256) void qcirc_kernel(
    const float* __restrict__ feats,  // (784,12)
    const float* __restrict__ qp,
    const float* __restrict__ kp,
    const float* __restrict__ vp,
    float* __restrict__ qkv)          // (3,784,12)
{
    __shared__ float lds[NSTATES];
    __shared__ float chs[NQ], shs[NQ];
    __shared__ float gc2[40], gs2[40], gcs[40];
    __shared__ float red[4][NQ];

    const int tid = threadIdx.x;
    const int p = blockIdx.x, b = blockIdx.y, c = blockIdx.z;
    const int bp = b * NPATCH + p;
    const float* params = (c == 0) ? qp : (c == 1) ? kp : vp;

    if (tid < NQ) {
        float h = 0.5f * feats[bp * NQ + tid];
        chs[tid] = cosf(h); shs[tid] = sinf(h);
    }
    if (tid < 40) {
        int l = tid / 20, g = tid - l * 20;
        float th = params[l * 32 + g];
        float ct = cosf(th), st = sinf(th);
        gc2[tid] = ct * ct; gs2[tid] = st * st; gcs[tid] = ct * st;
    }
    __syncthreads();

    // ---- init directly in R1 layout: idx = (r<<8)|tid ----
    float amp[16];
    {
        float hi = 1.0f;
        #pragma unroll
        for (int q = 4; q < 12; ++q)
            hi *= ((tid >> (11 - q)) & 1) ? shs[q] : chs[q];
        float f0c = chs[0], f0s = shs[0], f1c = chs[1], f1s = shs[1];
        float f2c = chs[2], f2s = shs[2], f3c = chs[3], f3s = shs[3];
        #pragma unroll
        for (int r = 0; r < 16; ++r) {
            amp[r] = ((r & 8) ? f0s : f0c) * ((r & 4) ? f1s : f1c) *
                     ((r & 2) ? f2s : f2c) * ((r & 1) ? f3s : f3c) * hi;
        }
    }

    // ---- 2 circuit layers, 7 runs each ----
    #pragma unroll
    for (int l = 0; l < 2; ++l) {
        const int bb = l * 20;
        // Run1 R={q0..q3}: gates p0 (0,1), p1 (2,3), p6 (0,2), p7 (1,3)
        apply_gate<8,4>(amp, gc2[bb+0], gs2[bb+0], gcs[bb+0]);
        apply_gate<2,1>(amp, gc2[bb+1], gs2[bb+1], gcs[bb+1]);
        apply_gate<8,2>(amp, gc2[bb+6], gs2[bb+6], gcs[bb+6]);
        apply_gate<4,1>(amp, gc2[bb+7], gs2[bb+7], gcs[bb+7]);
        relayout<RM1, RM2>(amp, lds, tid);
        // Run2 R={q4..q7}: p2 (4,5), p3 (6,7), p8 (4,6), p9 (5,7)
        apply_gate<8,4>(amp, gc2[bb+2], gs2[bb+2], gcs[bb+2]);
        apply_gate<2,1>(amp, gc2[bb+3], gs2[bb+3], gcs[bb+3]);
        apply_gate<8,2>(amp, gc2[bb+8], gs2[bb+8], gcs[bb+8]);
        apply_gate<4,1>(amp, gc2[bb+9], gs2[bb+9], gcs[bb+9]);
        relayout<RM2, RM3>(amp, lds, tid);
        // Run3 R={q8..q11}: p4 (8,9), p5 (10,11), p10 (8,10), p11 (9,11)
        apply_gate<8,4>(amp, gc2[bb+4],  gs2[bb+4],  gcs[bb+4]);
        apply_gate<2,1>(amp, gc2[bb+5],  gs2[bb+5],  gcs[bb+5]);
        apply_gate<8,2>(amp, gc2[bb+10], gs2[bb+10], gcs[bb+10]);
        apply_gate<4,1>(amp, gc2[bb+11], gs2[bb+11], gcs[bb+11]);
        relayout<RM3, RM4>(amp, lds, tid);
        // Run4 R={q0,1,4,5}: p12 (0,4), p13 (1,5)
        apply_gate<8,2>(amp, gc2[bb+12], gs2[bb+12], gcs[bb+12]);
        apply_gate<4,1>(amp, gc2[bb+13], gs2[bb+13], gcs[bb+13]);
        relayout<RM4, RM5>(amp, lds, tid);
        // Run5 R={q2,3,6,7}: p14 (2,6), p15 (3,7)
        apply_gate<8,2>(amp, gc2[bb+14], gs2[bb+14], gcs[bb+14]);
        apply_gate<4,1>(amp, gc2[bb+15], gs2[bb+15], gcs[bb+15]);
        relayout<RM5, RM6>(amp, lds, tid);
        // Run6 R={q0,1,8,9}: p16 (0,8), p17 (1,9)
        apply_gate<8,2>(amp, gc2[bb+16], gs2[bb+16], gcs[bb+16]);
        apply_gate<4,1>(amp, gc2[bb+17], gs2[bb+17], gcs[bb+17]);
        relayout<RM6, RM7>(amp, lds, tid);
        // Run7 R={q2,3,10,11}: p18 (2,10), p19 (3,11)
        apply_gate<8,2>(amp, gc2[bb+18], gs2[bb+18], gcs[bb+18]);
        apply_gate<4,1>(amp, gc2[bb+19], gs2[bb+19], gcs[bb+19]);
        if (l == 0) relayout<RM7, RM1>(amp, lds, tid);
    }

    // ---- expvals from registers (layout RM7: r bits = q2,q3,q10,q11;
    //      tid bits 7..0 = q0,q1,q4,q5,q6,q7,q8,q9) ----
    float pr[16];
    #pragma unroll
    for (int r = 0; r < 16; ++r) pr[r] = amp[r] * amp[r];
    float total = 0.0f, s2q = 0.0f, s3q = 0.0f, s10q = 0.0f, s11q = 0.0f;
    #pragma unroll
    for (int r = 0; r < 16; ++r) {
        total += pr[r];
        s2q  += (r & 8) ? -pr[r] : pr[r];
        s3q  += (r & 4) ? -pr[r] : pr[r];
        s10q += (r & 2) ? -pr[r] : pr[r];
        s11q += (r & 1) ? -pr[r] : pr[r];
    }
    float part[NQ];
    part[0]  = (tid & 128) ? -total : total;
    part[1]  = (tid & 64)  ? -total : total;
    part[2]  = s2q;
    part[3]  = s3q;
    part[4]  = (tid & 32)  ? -total : total;
    part[5]  = (tid & 16)  ? -total : total;
    part[6]  = (tid & 8)   ? -total : total;
    part[7]  = (tid & 4)   ? -total : total;
    part[8]  = (tid & 2)   ? -total : total;
    part[9]  = (tid & 1)   ? -total : total;
    part[10] = s10q;
    part[11] = s11q;

    #pragma unroll
    for (int q = 0; q < NQ; q++) {
        #pragma unroll
        for (int o = 32; o > 0; o >>= 1) part[q] += __shfl_down(part[q], o);
    }
    int lane = tid & 63, wv = tid >> 6;
    if (lane == 0) {
        #pragma unroll
        for (int q = 0; q < NQ; q++) red[wv][q] = part[q];
    }
    __syncthreads();
    if (tid < NQ) {
        float s = red[0][tid] + red[1][tid] + red[2][tid] + red[3][tid];
        qkv[((size_t)c * (NB * NPATCH) + bp) * NQ + tid] = s;
    }
}

// ---- Kernel 3: attention ---------------------------------------------------
__global__ __launch_bounds__(256) void attn_kernel(
    const float* __restrict__ qkv,    // (3,784,12)
    float* __restrict__ outb)         // (4,2352)
{
    int tid = threadIdx.x;
    int qp = blockIdx.x, b = blockIdx.y;
    const float* Q = qkv;
    const float* K = qkv + NB * NPATCH * NQ;
    const float* V = qkv + 2 * NB * NPATCH * NQ;

    __shared__ float redm[4], reds[4], redv[4][NQ];

    float qv[NQ];
    #pragma unroll
    for (int d = 0; d < NQ; d++) qv[d] = Q[(b * NPATCH + qp) * NQ + d];

    float score = -1e30f;
    if (tid < NPATCH) {
        float s = 0.0f;
        #pragma unroll
        for (int d = 0; d < NQ; d++) s += qv[d] * K[(b * NPATCH + tid) * NQ + d];
        score = s * SCALE_F;
    }
    float m = score;
    #pragma unroll
    for (int o = 32; o > 0; o >>= 1) m = fmaxf(m, __shfl_down(m, o));
    int lane = tid & 63, wv = tid >> 6;
    if (lane == 0) redm[wv] = m;
    __syncthreads();
    float maxv = fmaxf(fmaxf(redm[0], redm[1]), fmaxf(redm[2], redm[3]));

    float w = (tid < NPATCH) ? expf(score - maxv) : 0.0f;
    float sm = w;
    #pragma unroll
    for (int o = 32; o > 0; o >>= 1) sm += __shfl_down(sm, o);
    if (lane == 0) reds[wv] = sm;

    float part[NQ];
    #pragma unroll
    for (int d = 0; d < NQ; d++) part[d] = 0.0f;
    if (tid < NPATCH) {
        #pragma unroll
        for (int d = 0; d < NQ; d++) part[d] = w * V[(b * NPATCH + tid) * NQ + d];
    }
    #pragma unroll
    for (int d = 0; d < NQ; d++) {
        #pragma unroll
        for (int o = 32; o > 0; o >>= 1) part[d] += __shfl_down(part[d], o);
    }
    if (lane == 0) {
        #pragma unroll
        for (int d = 0; d < NQ; d++) redv[wv][d] = part[d];
    }
    __syncthreads();
    if (tid < NQ) {
        float sumv = reds[0] + reds[1] + reds[2] + reds[3];
        float s = redv[0][tid] + redv[1][tid] + redv[2][tid] + redv[3][tid];
        outb[(size_t)b * FEATDIM + qp * NQ + tid] = s / sumv;
    }
}

// ---- Kernel 4: classifier --------------------------------------------------
__global__ __launch_bounds__(256) void cls_kernel(
    const float* __restrict__ outb,   // (4,2352)
    const float* __restrict__ Wc,     // (1000,2352)
    const float* __restrict__ bc,     // (1000,)
    float* __restrict__ logits)       // (4,1000)
{
    int o = blockIdx.x, tid = threadIdx.x;
    float acc[NB] = {0.0f, 0.0f, 0.0f, 0.0f};
    const float* wrow = Wc + (size_t)o * FEATDIM;
    for (int j = tid; j < FEATDIM; j += 256) {
        float w = wrow[j];
        #pragma unroll
        for (int b = 0; b < NB; b++) acc[b] += w * outb[(size_t)b * FEATDIM + j];
    }
    #pragma unroll
    for (int b = 0; b < NB; b++) {
        #pragma unroll
        for (int off = 32; off > 0; off >>= 1) acc[b] += __shfl_down(acc[b], off);
    }
    __shared__ float red[4][NB];
    int lane = tid & 63, wv = tid >> 6;
    if (lane == 0) {
        #pragma unroll
        for (int b = 0; b < NB; b++) red[wv][b] = acc[b];
    }
    __syncthreads();
    if (tid < NB) {
        float s = red[0][tid] + red[1][tid] + red[2][tid] + red[3][tid];
        logits[(size_t)tid * NCLS + o] = s + bc[o];
    }
}

// ---- Launch ----------------------------------------------------------------
extern "C" void kernel_launch(void* const* d_in, const int* in_sizes, int n_in,
                              void* d_out, int out_size, void* d_ws, size_t ws_size,
                              hipStream_t stream) {
    const float* x     = (const float*)d_in[0];
    const float* Wp    = (const float*)d_in[1];
    const float* bproj = (const float*)d_in[2];
    const float* qp    = (const float*)d_in[3];
    const float* kp    = (const float*)d_in[4];
    const float* vp    = (const float*)d_in[5];
    const float* Wc    = (const float*)d_in[6];
    const float* bc    = (const float*)d_in[7];
    float* logits = (float*)d_out;

    float* ws    = (float*)d_ws;
    float* feats = ws;                       // 784*12      = 9408 floats
    float* qkv   = ws + 9408;                // 3*784*12    = 28224 floats
    float* outb  = ws + 9408 + 28224;        // 4*2352      = 9408 floats

    proj_kernel <<<dim3(NPATCH, NB),    256, 0, stream>>>(x, Wp, bproj, feats);
    qcirc_kernel<<<dim3(NPATCH, NB, 3), 256, 0, stream>>>(feats, qp, kp, vp, qkv);
    attn_kernel <<<dim3(NPATCH, NB),    256, 0, stream>>>(qkv, outb);
    cls_kernel  <<<NCLS,                256, 0, stream>>>(outb, Wc, bc, logits);
}

// Round 3
// 146.521 us; speedup vs baseline: 1.4304x; 1.0082x over previous
//
#include <hip/hip_runtime.h>
#include <math.h>

// ---- Problem constants -----------------------------------------------------
#define NQ        12
#define NSTATES   4096
#define NPS       14
#define NPATCH    196
#define NB        4
#define NCLS      1000
#define FEATDIM   2352           // 196*12
#define SCALE_F   0.28867513459481287f  // 1/sqrt(12)
#define STRIDE    20             // floats per thread region (16 amps + 4 pad); 80B = 5*16B aligned

// Run layouts (position masks; qubit q <-> state bit position 11-q).
// R1: q0-3, R2: q4-7, R3: q8-11, R4: q0,1,4,5, R5: q2,3,6,7, R6: q0,1,8,9, R7: q2,3,10,11
#define RM1 0xF00
#define RM2 0x0F0
#define RM3 0x00F
#define RM4 0xCC0
#define RM5 0x330
#define RM6 0xC0C
#define RM7 0x303

// ---- constexpr address algebra ---------------------------------------------
// Conventions (identical to the verified round-1 kernel):
//  reg bit 3 <-> highest position in RM (smallest qubit of the set)
//  tid bit 7 <-> highest position not in RM
// Storage for relayout out of layout X: addr_float = 20*t_X + r_X.
constexpr int nth_set_desc(int mask, int n) {
    int cnt = 0;
    for (int pos = 11; pos >= 0; --pos)
        if (mask & (1 << pos)) { if (cnt == n) return pos; ++cnt; }
    return -1;
}
constexpr int nth_clr_desc(int mask, int n) {
    int cnt = 0;
    for (int pos = 11; pos >= 0; --pos)
        if (!(mask & (1 << pos))) { if (cnt == n) return pos; ++cnt; }
    return -1;
}
// weight of state-bit at `pos` in the X-storage address (20*t + r)
constexpr int x_contrib(int RMX, int pos) {
    if (RMX & (1 << pos)) {
        int k = 0;                              // rank among RMX, descending
        for (int p = 11; p > pos; --p) if (RMX & (1 << p)) ++k;
        return 1 << (3 - k);
    } else {
        int m = 0;                              // rank among ~RMX, descending
        for (int p = 11; p > pos; --p) if (!(RMX & (1 << p))) ++m;
        return STRIDE << (7 - m);
    }
}
// contribution of reader tid bit p (layout Y=RMB) in X-storage address
constexpr int read_tbit(int RMA, int RMB, int p) {
    return x_contrib(RMA, nth_clr_desc(RMB, 7 - p));
}
// immediate offset (floats) for reader reg r (layout Y=RMB)
constexpr int read_imm(int RMA, int RMB, int r) {
    int imm = 0;
    for (int j = 0; j < 4; ++j)
        if (r & (1 << j)) imm += x_contrib(RMA, nth_set_desc(RMB, 3 - j));
    return imm;
}

template<int RMA, int RMB>
__device__ __forceinline__ void relayout(float amp[16], float* lds, int tid) {
    float4* dst = (float4*)(lds + STRIDE * tid);
    dst[0] = make_float4(amp[0],  amp[1],  amp[2],  amp[3]);
    dst[1] = make_float4(amp[4],  amp[5],  amp[6],  amp[7]);
    dst[2] = make_float4(amp[8],  amp[9],  amp[10], amp[11]);
    dst[3] = make_float4(amp[12], amp[13], amp[14], amp[15]);
    __syncthreads();
    int base = 0;
    #pragma unroll
    for (int p = 0; p < 8; ++p)
        base += (tid & (1 << p)) ? read_tbit(RMA, RMB, p) : 0;
    #pragma unroll
    for (int r = 0; r < 16; ++r)
        amp[r] = lds[base + read_imm(RMA, RMB, r)];
    __syncthreads();
}

// RBS gate on register bits MI (first qubit) / MJ (second qubit).
template<int MI, int MJ>
__device__ __forceinline__ void apply_gate(float amp[16], float c2, float s2, float cs) {
    #pragma unroll
    for (int m = 0; m < 16; ++m) {
        if (m & (MI | MJ)) continue;
        float a0 = amp[m], a1 = amp[m | MJ], a2 = amp[m | MI], a3 = amp[m | MI | MJ];
        float du = a0 - a1, dv = a3 - a2;
        amp[m]           = c2 * a0 + s2 * a1 + cs * dv;
        amp[m | MJ]      = s2 * a0 + c2 * a1 - cs * dv;
        amp[m | MI]      = c2 * a2 + s2 * a3 + cs * du;
        amp[m | MI | MJ] = s2 * a2 + c2 * a3 - cs * du;
    }
}

// ---- Kernel: fused projection + quantum circuit ----------------------------
// grid (196, 4, 3), block 256.
__global__ __launch_bounds__(256) void qcirc_kernel(
    const float* __restrict__ x,      // (4,3,224,224)
    const float* __restrict__ Wp,     // (12,256)
    const float* __restrict__ bproj,  // (12,)
    const float* __restrict__ qp,
    const float* __restrict__ kp,
    const float* __restrict__ vp,
    float* __restrict__ qkv)          // (3,784,12)
{
    __shared__ __align__(16) float lds[256 * STRIDE];
    __shared__ float chs[NQ], shs[NQ];
    __shared__ float gc2[40], gs2[40], gcs[40];
    __shared__ float red[4][NQ];

    const int tid = threadIdx.x;
    const int p = blockIdx.x, b = blockIdx.y, c = blockIdx.z;
    const int bp = b * NPATCH + p;
    const float* params = (c == 0) ? qp : (c == 1) ? kp : vp;

    // ---- projection (fused): pixel tid of this patch ----
    {
        int py = p / NPS, px = p % NPS;
        int row = py * 16 + (tid >> 4), col = px * 16 + (tid & 15);
        const float* xb = x + (size_t)b * 3 * 224 * 224;
        int off = row * 224 + col;
        float pix = (xb[off] + xb[224*224 + off] + xb[2*224*224 + off]) * (1.0f/3.0f);

        float part[NQ];
        #pragma unroll
        for (int q = 0; q < NQ; q++) part[q] = pix * Wp[q * 256 + tid];
        #pragma unroll
        for (int q = 0; q < NQ; q++) {
            #pragma unroll
            for (int o = 32; o > 0; o >>= 1) part[q] += __shfl_down(part[q], o);
        }
        int lane = tid & 63, wv = tid >> 6;
        if (lane == 0) {
            #pragma unroll
            for (int q = 0; q < NQ; q++) red[wv][q] = part[q];
        }
    }
    if (tid < 40) {
        int l = tid / 20, g = tid - l * 20;
        float th = params[l * 32 + g];
        float ct = cosf(th), st = sinf(th);
        gc2[tid] = ct * ct; gs2[tid] = st * st; gcs[tid] = ct * st;
    }
    __syncthreads();
    if (tid < NQ) {
        float f = red[0][tid] + red[1][tid] + red[2][tid] + red[3][tid] + bproj[tid];
        float h = 0.5f * f;
        chs[tid] = cosf(h); shs[tid] = sinf(h);
    }
    __syncthreads();

    // ---- init in R1 layout ----
    float amp[16];
    {
        float hi = 1.0f;
        #pragma unroll
        for (int q = 4; q < 12; ++q)
            hi *= ((tid >> (11 - q)) & 1) ? shs[q] : chs[q];
        float f0c = chs[0], f0s = shs[0], f1c = chs[1], f1s = shs[1];
        float f2c = chs[2], f2s = shs[2], f3c = chs[3], f3s = shs[3];
        #pragma unroll
        for (int r = 0; r < 16; ++r) {
            amp[r] = ((r & 8) ? f0s : f0c) * ((r & 4) ? f1s : f1c) *
                     ((r & 2) ? f2s : f2c) * ((r & 1) ? f3s : f3c) * hi;
        }
    }

    // ---- 2 circuit layers, 7 runs each (schedule identical to verified v1) ----
    #pragma unroll
    for (int l = 0; l < 2; ++l) {
        const int bb = l * 20;
        // Run1 R={q0..q3}: p0 (0,1), p1 (2,3), p6 (0,2), p7 (1,3)
        apply_gate<8,4>(amp, gc2[bb+0], gs2[bb+0], gcs[bb+0]);
        apply_gate<2,1>(amp, gc2[bb+1], gs2[bb+1], gcs[bb+1]);
        apply_gate<8,2>(amp, gc2[bb+6], gs2[bb+6], gcs[bb+6]);
        apply_gate<4,1>(amp, gc2[bb+7], gs2[bb+7], gcs[bb+7]);
        relayout<RM1, RM2>(amp, lds, tid);
        // Run2 R={q4..q7}: p2 (4,5), p3 (6,7), p8 (4,6), p9 (5,7)
        apply_gate<8,4>(amp, gc2[bb+2], gs2[bb+2], gcs[bb+2]);
        apply_gate<2,1>(amp, gc2[bb+3], gs2[bb+3], gcs[bb+3]);
        apply_gate<8,2>(amp, gc2[bb+8], gs2[bb+8], gcs[bb+8]);
        apply_gate<4,1>(amp, gc2[bb+9], gs2[bb+9], gcs[bb+9]);
        relayout<RM2, RM3>(amp, lds, tid);
        // Run3 R={q8..q11}: p4 (8,9), p5 (10,11), p10 (8,10), p11 (9,11)
        apply_gate<8,4>(amp, gc2[bb+4],  gs2[bb+4],  gcs[bb+4]);
        apply_gate<2,1>(amp, gc2[bb+5],  gs2[bb+5],  gcs[bb+5]);
        apply_gate<8,2>(amp, gc2[bb+10], gs2[bb+10], gcs[bb+10]);
        apply_gate<4,1>(amp, gc2[bb+11], gs2[bb+11], gcs[bb+11]);
        relayout<RM3, RM4>(amp, lds, tid);
        // Run4 R={q0,1,4,5}: p12 (0,4), p13 (1,5)
        apply_gate<8,2>(amp, gc2[bb+12], gs2[bb+12], gcs[bb+12]);
        apply_gate<4,1>(amp, gc2[bb+13], gs2[bb+13], gcs[bb+13]);
        relayout<RM4, RM5>(amp, lds, tid);
        // Run5 R={q2,3,6,7}: p14 (2,6), p15 (3,7)
        apply_gate<8,2>(amp, gc2[bb+14], gs2[bb+14], gcs[bb+14]);
        apply_gate<4,1>(amp, gc2[bb+15], gs2[bb+15], gcs[bb+15]);
        relayout<RM5, RM6>(amp, lds, tid);
        // Run6 R={q0,1,8,9}: p16 (0,8), p17 (1,9)
        apply_gate<8,2>(amp, gc2[bb+16], gs2[bb+16], gcs[bb+16]);
        apply_gate<4,1>(amp, gc2[bb+17], gs2[bb+17], gcs[bb+17]);
        relayout<RM6, RM7>(amp, lds, tid);
        // Run7 R={q2,3,10,11}: p18 (2,10), p19 (3,11)
        apply_gate<8,2>(amp, gc2[bb+18], gs2[bb+18], gcs[bb+18]);
        apply_gate<4,1>(amp, gc2[bb+19], gs2[bb+19], gcs[bb+19]);
        if (l == 0) relayout<RM7, RM1>(amp, lds, tid);
    }

    // ---- expvals (RM7 layout: r bits = q2,q3,q10,q11; tid bits 7..0 = q0,q1,q4..q9) ----
    float pr[16];
    #pragma unroll
    for (int r = 0; r < 16; ++r) pr[r] = amp[r] * amp[r];
    float total = 0.0f, s2q = 0.0f, s3q = 0.0f, s10q = 0.0f, s11q = 0.0f;
    #pragma unroll
    for (int r = 0; r < 16; ++r) {
        total += pr[r];
        s2q  += (r & 8) ? -pr[r] : pr[r];
        s3q  += (r & 4) ? -pr[r] : pr[r];
        s10q += (r & 2) ? -pr[r] : pr[r];
        s11q += (r & 1) ? -pr[r] : pr[r];
    }
    float part[NQ];
    part[0]  = (tid & 128) ? -total : total;
    part[1]  = (tid & 64)  ? -total : total;
    part[2]  = s2q;
    part[3]  = s3q;
    part[4]  = (tid & 32)  ? -total : total;
    part[5]  = (tid & 16)  ? -total : total;
    part[6]  = (tid & 8)   ? -total : total;
    part[7]  = (tid & 4)   ? -total : total;
    part[8]  = (tid & 2)   ? -total : total;
    part[9]  = (tid & 1)   ? -total : total;
    part[10] = s10q;
    part[11] = s11q;

    #pragma unroll
    for (int q = 0; q < NQ; q++) {
        #pragma unroll
        for (int o = 32; o > 0; o >>= 1) part[q] += __shfl_down(part[q], o);
    }
    int lane = tid & 63, wv = tid >> 6;
    if (lane == 0) {
        #pragma unroll
        for (int q = 0; q < NQ; q++) red[wv][q] = part[q];
    }
    __syncthreads();
    if (tid < NQ) {
        float s = red[0][tid] + red[1][tid] + red[2][tid] + red[3][tid];
        qkv[((size_t)c * (NB * NPATCH) + bp) * NQ + tid] = s;
    }
}

// ---- Kernel: attention ------------------------------------------------------
__global__ __launch_bounds__(256) void attn_kernel(
    const float* __restrict__ qkv,    // (3,784,12)
    float* __restrict__ outb)         // (4,2352)
{
    int tid = threadIdx.x;
    int qp = blockIdx.x, b = blockIdx.y;
    const float* Q = qkv;
    const float* K = qkv + NB * NPATCH * NQ;
    const float* V = qkv + 2 * NB * NPATCH * NQ;

    __shared__ float redm[4], reds[4], redv[4][NQ];

    float qv[NQ];
    #pragma unroll
    for (int d = 0; d < NQ; d++) qv[d] = Q[(b * NPATCH + qp) * NQ + d];

    float score = -1e30f;
    if (tid < NPATCH) {
        float s = 0.0f;
        #pragma unroll
        for (int d = 0; d < NQ; d++) s += qv[d] * K[(b * NPATCH + tid) * NQ + d];
        score = s * SCALE_F;
    }
    float m = score;
    #pragma unroll
    for (int o = 32; o > 0; o >>= 1) m = fmaxf(m, __shfl_down(m, o));
    int lane = tid & 63, wv = tid >> 6;
    if (lane == 0) redm[wv] = m;
    __syncthreads();
    float maxv = fmaxf(fmaxf(redm[0], redm[1]), fmaxf(redm[2], redm[3]));

    float w = (tid < NPATCH) ? expf(score - maxv) : 0.0f;
    float sm = w;
    #pragma unroll
    for (int o = 32; o > 0; o >>= 1) sm += __shfl_down(sm, o);
    if (lane == 0) reds[wv] = sm;

    float part[NQ];
    #pragma unroll
    for (int d = 0; d < NQ; d++) part[d] = 0.0f;
    if (tid < NPATCH) {
        #pragma unroll
        for (int d = 0; d < NQ; d++) part[d] = w * V[(b * NPATCH + tid) * NQ + d];
    }
    #pragma unroll
    for (int d = 0; d < NQ; d++) {
        #pragma unroll
        for (int o = 32; o > 0; o >>= 1) part[d] += __shfl_down(part[d], o);
    }
    if (lane == 0) {
        #pragma unroll
        for (int d = 0; d < NQ; d++) redv[wv][d] = part[d];
    }
    __syncthreads();
    if (tid < NQ) {
        float sumv = reds[0] + reds[1] + reds[2] + reds[3];
        float s = redv[0][tid] + redv[1][tid] + redv[2][tid] + redv[3][tid];
        outb[(size_t)b * FEATDIM + qp * NQ + tid] = s / sumv;
    }
}

// ---- Kernel: classifier -----------------------------------------------------
__global__ __launch_bounds__(256) void cls_kernel(
    const float* __restrict__ outb,   // (4,2352)
    const float* __restrict__ Wc,     // (1000,2352)
    const float* __restrict__ bc,     // (1000,)
    float* __restrict__ logits)       // (4,1000)
{
    int o = blockIdx.x, tid = threadIdx.x;
    float acc[NB] = {0.0f, 0.0f, 0.0f, 0.0f};
    const float* wrow = Wc + (size_t)o * FEATDIM;
    for (int j = tid; j < FEATDIM; j += 256) {
        float w = wrow[j];
        #pragma unroll
        for (int b = 0; b < NB; b++) acc[b] += w * outb[(size_t)b * FEATDIM + j];
    }
    #pragma unroll
    for (int b = 0; b < NB; b++) {
        #pragma unroll
        for (int off = 32; off > 0; off >>= 1) acc[b] += __shfl_down(acc[b], off);
    }
    __shared__ float red[4][NB];
    int lane = tid & 63, wv = tid >> 6;
    if (lane == 0) {
        #pragma unroll
        for (int b = 0; b < NB; b++) red[wv][b] = acc[b];
    }
    __syncthreads();
    if (tid < NB) {
        float s = red[0][tid] + red[1][tid] + red[2][tid] + red[3][tid];
        logits[(size_t)tid * NCLS + o] = s + bc[o];
    }
}

// ---- Launch ----------------------------------------------------------------
extern "C" void kernel_launch(void* const* d_in, const int* in_sizes, int n_in,
                              void* d_out, int out_size, void* d_ws, size_t ws_size,
                              hipStream_t stream) {
    const float* x     = (const float*)d_in[0];
    const float* Wp    = (const float*)d_in[1];
    const float* bproj = (const float*)d_in[2];
    const float* qp    = (const float*)d_in[3];
    const float* kp    = (const float*)d_in[4];
    const float* vp    = (const float*)d_in[5];
    const float* Wc    = (const float*)d_in[6];
    const float* bc    = (const float*)d_in[7];
    float* logits = (float*)d_out;

    float* ws   = (float*)d_ws;
    float* qkv  = ws;                 // 3*784*12 = 28224 floats
    float* outb = ws + 28224;         // 4*2352   =  9408 floats

    qcirc_kernel<<<dim3(NPATCH, NB, 3), 256, 0, stream>>>(x, Wp, bproj, qp, kp, vp, qkv);
    attn_kernel <<<dim3(NPATCH, NB),    256, 0, stream>>>(qkv, outb);
    cls_kernel  <<<NCLS,                256, 0, stream>>>(outb, Wc, bc, logits);
}

// Round 4
// 132.494 us; speedup vs baseline: 1.5818x; 1.1059x over previous
//
#include <hip/hip_runtime.h>
#include <math.h>

// ---- Problem constants -----------------------------------------------------
#define NQ        12
#define NSTATES   4096
#define NPS       14
#define NPATCH    196
#define NB        4
#define NCLS      1000
#define FEATDIM   2352           // 196*12
#define SCALE_F   0.28867513459481287f  // 1/sqrt(12)
#define STRIDE    17             // floats per thread region; odd -> 17t mod 32 hits all banks

// Run layouts (position masks; qubit q <-> state bit position 11-q).
#define RM1 0xF00   // q0-3
#define RM2 0x0F0   // q4-7
#define RM3 0x00F   // q8-11
#define RM4 0xCC0   // q0,1,4,5
#define RM5 0x330   // q2,3,6,7
#define RM6 0xC0C   // q0,1,8,9
#define RM7 0x303   // q2,3,10,11

// ---- constexpr address algebra ---------------------------------------------
// reg bit 3 <-> highest position in RM; tid bit 7 <-> highest position not in RM.
// Storage out of layout X: addr_float = STRIDE*t_X + r_X.
constexpr int nth_set_desc(int mask, int n) {
    int cnt = 0;
    for (int pos = 11; pos >= 0; --pos)
        if (mask & (1 << pos)) { if (cnt == n) return pos; ++cnt; }
    return -1;
}
constexpr int nth_clr_desc(int mask, int n) {
    int cnt = 0;
    for (int pos = 11; pos >= 0; --pos)
        if (!(mask & (1 << pos))) { if (cnt == n) return pos; ++cnt; }
    return -1;
}
constexpr int x_contrib(int RMX, int pos) {
    if (RMX & (1 << pos)) {
        int k = 0;
        for (int p = 11; p > pos; --p) if (RMX & (1 << p)) ++k;
        return 1 << (3 - k);
    } else {
        int m = 0;
        for (int p = 11; p > pos; --p) if (!(RMX & (1 << p))) ++m;
        return STRIDE << (7 - m);
    }
}
constexpr int read_tbit(int RMA, int RMB, int p) {
    return x_contrib(RMA, nth_clr_desc(RMB, 7 - p));
}
constexpr int read_imm(int RMA, int RMB, int r) {
    int imm = 0;
    for (int j = 0; j < 4; ++j)
        if (r & (1 << j)) imm += x_contrib(RMA, nth_set_desc(RMB, 3 - j));
    return imm;
}

// Single barrier per relayout: writes go to `buf`, which alternates each call;
// relayout i's writes can't race relayout i-1's reads (other buffer, separated
// by relayout i-1's barrier).
template<int RMA, int RMB>
__device__ __forceinline__ void relayout(float amp[16], float* buf, int tid) {
    float* w = buf + STRIDE * tid;
    #pragma unroll
    for (int r = 0; r < 16; ++r) w[r] = amp[r];
    __syncthreads();
    int base = 0;
    #pragma unroll
    for (int p = 0; p < 8; ++p)
        base += (tid & (1 << p)) ? read_tbit(RMA, RMB, p) : 0;
    #pragma unroll
    for (int r = 0; r < 16; ++r)
        amp[r] = buf[base + read_imm(RMA, RMB, r)];
}

// RBS gate on register bits MI (first qubit) / MJ (second qubit).
template<int MI, int MJ>
__device__ __forceinline__ void apply_gate(float amp[16], float c2, float s2, float cs) {
    #pragma unroll
    for (int m = 0; m < 16; ++m) {
        if (m & (MI | MJ)) continue;
        float a0 = amp[m], a1 = amp[m | MJ], a2 = amp[m | MI], a3 = amp[m | MI | MJ];
        float du = a0 - a1, dv = a3 - a2;
        amp[m]           = c2 * a0 + s2 * a1 + cs * dv;
        amp[m | MJ]      = s2 * a0 + c2 * a1 - cs * dv;
        amp[m | MI]      = c2 * a2 + s2 * a3 + cs * du;
        amp[m | MI | MJ] = s2 * a2 + c2 * a3 - cs * du;
    }
}

__device__ const int SLOT[12] = {0,0,7,8,6,5,4,3,2,1,9,10};

// ---- Kernel: fused projection + quantum circuit ----------------------------
// grid (196, 4, 3), block 256.
__global__ __launch_bounds__(256) void qcirc_kernel(
    const float* __restrict__ x,      // (4,3,224,224)
    const float* __restrict__ Wp,     // (12,256)
    const float* __restrict__ bproj,  // (12,)
    const float* __restrict__ qp,
    const float* __restrict__ kp,
    const float* __restrict__ vp,
    float* __restrict__ qkv)          // (3,784,12)
{
    __shared__ __align__(16) float bufA[256 * STRIDE];
    __shared__ __align__(16) float bufB[256 * STRIDE];
    __shared__ float chs[NQ], shs[NQ];
    __shared__ float gc2[40], gs2[40], gcs[40];
    __shared__ float red11[4][11];
    __shared__ float rscr[12 * 16];

    const int tid = threadIdx.x;
    const int p = blockIdx.x, b = blockIdx.y, c = blockIdx.z;
    const int bp = b * NPATCH + p;
    const float* params = (c == 0) ? qp : (c == 1) ? kp : vp;

    // ---- projection (fused), reduction via LDS transpose in bufA ----
    {
        int py = p / NPS, px = p % NPS;
        int row = py * 16 + (tid >> 4), col = px * 16 + (tid & 15);
        const float* xb = x + (size_t)b * 3 * 224 * 224;
        int off = row * 224 + col;
        float pix = (xb[off] + xb[224*224 + off] + xb[2*224*224 + off]) * (1.0f/3.0f);
        #pragma unroll
        for (int q = 0; q < NQ; q++) bufA[q * 264 + tid] = pix * Wp[q * 256 + tid];
    }
    if (tid < 40) {
        int l = tid / 20, g = tid - l * 20;
        float th = params[l * 32 + g];
        float ct = cosf(th), st = sinf(th);
        gc2[tid] = ct * ct; gs2[tid] = st * st; gcs[tid] = ct * st;
    }
    __syncthreads();
    if (tid < 192) {
        int q = tid >> 4, cc = tid & 15;
        const float4* src = (const float4*)(bufA + q * 264 + cc * 16);
        float4 v0 = src[0], v1 = src[1], v2 = src[2], v3 = src[3];
        rscr[tid] = (v0.x+v0.y+v0.z+v0.w) + (v1.x+v1.y+v1.z+v1.w) +
                    (v2.x+v2.y+v2.z+v2.w) + (v3.x+v3.y+v3.z+v3.w);
    }
    __syncthreads();
    if (tid < NQ) {
        float s = 0.0f;
        #pragma unroll
        for (int j = 0; j < 16; ++j) s += rscr[tid * 16 + j];
        float h = 0.5f * (s + bproj[tid]);
        chs[tid] = cosf(h); shs[tid] = sinf(h);
    }
    __syncthreads();

    // ---- init in R1 layout (r bits = q0..q3; tid bits 7..0 = q4..q11) ----
    float amp[16];
    {
        float hi = 1.0f;
        #pragma unroll
        for (int q = 4; q < 12; ++q)
            hi *= ((tid >> (11 - q)) & 1) ? shs[q] : chs[q];
        float f0c = chs[0], f0s = shs[0], f1c = chs[1], f1s = shs[1];
        float f2c = chs[2], f2s = shs[2], f3c = chs[3], f3s = shs[3];
        #pragma unroll
        for (int r = 0; r < 16; ++r) {
            amp[r] = ((r & 8) ? f0s : f0c) * ((r & 4) ? f1s : f1c) *
                     ((r & 2) ? f2s : f2c) * ((r & 1) ? f3s : f3c) * hi;
        }
    }

    // ---- 2 circuit layers, 7 runs each; buffers alternate A,B,A,B,... ----
    #pragma unroll
    for (int l = 0; l < 2; ++l) {
        const int bb = l * 20;
        float* const s1 = l ? bufB : bufA;   // relayout ordinal parity per layer
        float* const s2 = l ? bufA : bufB;
        // Run1 R={q0..q3}: p0 (0,1), p1 (2,3), p6 (0,2), p7 (1,3)
        apply_gate<8,4>(amp, gc2[bb+0], gs2[bb+0], gcs[bb+0]);
        apply_gate<2,1>(amp, gc2[bb+1], gs2[bb+1], gcs[bb+1]);
        apply_gate<8,2>(amp, gc2[bb+6], gs2[bb+6], gcs[bb+6]);
        apply_gate<4,1>(amp, gc2[bb+7], gs2[bb+7], gcs[bb+7]);
        relayout<RM1, RM2>(amp, s1, tid);
        // Run2 R={q4..q7}: p2 (4,5), p3 (6,7), p8 (4,6), p9 (5,7)
        apply_gate<8,4>(amp, gc2[bb+2], gs2[bb+2], gcs[bb+2]);
        apply_gate<2,1>(amp, gc2[bb+3], gs2[bb+3], gcs[bb+3]);
        apply_gate<8,2>(amp, gc2[bb+8], gs2[bb+8], gcs[bb+8]);
        apply_gate<4,1>(amp, gc2[bb+9], gs2[bb+9], gcs[bb+9]);
        relayout<RM2, RM3>(amp, s2, tid);
        // Run3 R={q8..q11}: p4 (8,9), p5 (10,11), p10 (8,10), p11 (9,11)
        apply_gate<8,4>(amp, gc2[bb+4],  gs2[bb+4],  gcs[bb+4]);
        apply_gate<2,1>(amp, gc2[bb+5],  gs2[bb+5],  gcs[bb+5]);
        apply_gate<8,2>(amp, gc2[bb+10], gs2[bb+10], gcs[bb+10]);
        apply_gate<4,1>(amp, gc2[bb+11], gs2[bb+11], gcs[bb+11]);
        relayout<RM3, RM4>(amp, s1, tid);
        // Run4 R={q0,1,4,5}: p12 (0,4), p13 (1,5)
        apply_gate<8,2>(amp, gc2[bb+12], gs2[bb+12], gcs[bb+12]);
        apply_gate<4,1>(amp, gc2[bb+13], gs2[bb+13], gcs[bb+13]);
        relayout<RM4, RM5>(amp, s2, tid);
        // Run5 R={q2,3,6,7}: p14 (2,6), p15 (3,7)
        apply_gate<8,2>(amp, gc2[bb+14], gs2[bb+14], gcs[bb+14]);
        apply_gate<4,1>(amp, gc2[bb+15], gs2[bb+15], gcs[bb+15]);
        relayout<RM5, RM6>(amp, s1, tid);
        // Run6 R={q0,1,8,9}: p16 (0,8), p17 (1,9)
        apply_gate<8,2>(amp, gc2[bb+16], gs2[bb+16], gcs[bb+16]);
        apply_gate<4,1>(amp, gc2[bb+17], gs2[bb+17], gcs[bb+17]);
        relayout<RM6, RM7>(amp, s2, tid);
        // Run7 R={q2,3,10,11}: p18 (2,10), p19 (3,11)
        apply_gate<8,2>(amp, gc2[bb+18], gs2[bb+18], gcs[bb+18]);
        apply_gate<4,1>(amp, gc2[bb+19], gs2[bb+19], gcs[bb+19]);
        if (l == 0) relayout<RM7, RM1>(amp, s1, tid);
    }

    // ---- expvals. RM7: r bits = q2,q3,q10,q11; tid bits 7..0 = q0,q1,q4..q9.
    // Signed butterfly over lane bits 0..5; wave bits 6,7 via LDS.
    float T = 0.0f, S2 = 0.0f, S3 = 0.0f, S10 = 0.0f, S11 = 0.0f;
    #pragma unroll
    for (int r = 0; r < 16; ++r) {
        float pp = amp[r] * amp[r];
        T += pp;
        S2  += (r & 8) ? -pp : pp;
        S3  += (r & 4) ? -pp : pp;
        S10 += (r & 2) ? -pp : pp;
        S11 += (r & 1) ? -pp : pp;
    }
    float A = T;
    float M[6];
    #pragma unroll
    for (int pbit = 0; pbit < 6; ++pbit) {
        int msk = 1 << pbit;
        float Ap = __shfl_xor(A, msk);
        float d  = A - Ap;
        M[pbit] = (tid & msk) ? -d : d;
        A += Ap;
        #pragma unroll
        for (int k = 0; k < 6; ++k)
            if (k < pbit) M[k] += __shfl_xor(M[k], msk);
        S2  += __shfl_xor(S2,  msk);
        S3  += __shfl_xor(S3,  msk);
        S10 += __shfl_xor(S10, msk);
        S11 += __shfl_xor(S11, msk);
    }
    int lane = tid & 63, wv = tid >> 6;
    if (lane == 0) {
        red11[wv][0] = A;
        red11[wv][1] = M[0]; red11[wv][2] = M[1]; red11[wv][3] = M[2];
        red11[wv][4] = M[3]; red11[wv][5] = M[4]; red11[wv][6] = M[5];
        red11[wv][7] = S2;   red11[wv][8] = S3;
        red11[wv][9] = S10;  red11[wv][10] = S11;
    }
    __syncthreads();
    if (tid < NQ) {
        int sl = SLOT[tid];
        float s = 0.0f;
        #pragma unroll
        for (int w = 0; w < 4; ++w) {
            float v = red11[w][sl];
            if (tid == 0 && (w & 2)) v = -v;   // q0 sign = wave bit 1 (tid bit 7)
            if (tid == 1 && (w & 1)) v = -v;   // q1 sign = wave bit 0 (tid bit 6)
            s += v;
        }
        qkv[((size_t)c * (NB * NPATCH) + bp) * NQ + tid] = s;
    }
}

// ---- Kernel: attention ------------------------------------------------------
__global__ __launch_bounds__(256) void attn_kernel(
    const float* __restrict__ qkv,    // (3,784,12)
    float* __restrict__ outb)         // (4,2352)
{
    int tid = threadIdx.x;
    int qp = blockIdx.x, b = blockIdx.y;
    const float* Q = qkv;
    const float* K = qkv + NB * NPATCH * NQ;
    const float* V = qkv + 2 * NB * NPATCH * NQ;

    __shared__ float redm[4], reds[4], redv[4][NQ];

    float qv[NQ];
    #pragma unroll
    for (int d = 0; d < NQ; d++) qv[d] = Q[(b * NPATCH + qp) * NQ + d];

    float score = -1e30f;
    if (tid < NPATCH) {
        float s = 0.0f;
        #pragma unroll
        for (int d = 0; d < NQ; d++) s += qv[d] * K[(b * NPATCH + tid) * NQ + d];
        score = s * SCALE_F;
    }
    float m = score;
    #pragma unroll
    for (int o = 32; o > 0; o >>= 1) m = fmaxf(m, __shfl_down(m, o));
    int lane = tid & 63, wv = tid >> 6;
    if (lane == 0) redm[wv] = m;
    __syncthreads();
    float maxv = fmaxf(fmaxf(redm[0], redm[1]), fmaxf(redm[2], redm[3]));

    float w = (tid < NPATCH) ? expf(score - maxv) : 0.0f;
    float sm = w;
    #pragma unroll
    for (int o = 32; o > 0; o >>= 1) sm += __shfl_down(sm, o);
    if (lane == 0) reds[wv] = sm;

    float part[NQ];
    #pragma unroll
    for (int d = 0; d < NQ; d++) part[d] = 0.0f;
    if (tid < NPATCH) {
        #pragma unroll
        for (int d = 0; d < NQ; d++) part[d] = w * V[(b * NPATCH + tid) * NQ + d];
    }
    #pragma unroll
    for (int d = 0; d < NQ; d++) {
        #pragma unroll
        for (int o = 32; o > 0; o >>= 1) part[d] += __shfl_down(part[d], o);
    }
    if (lane == 0) {
        #pragma unroll
        for (int d = 0; d < NQ; d++) redv[wv][d] = part[d];
    }
    __syncthreads();
    if (tid < NQ) {
        float sumv = reds[0] + reds[1] + reds[2] + reds[3];
        float s = redv[0][tid] + redv[1][tid] + redv[2][tid] + redv[3][tid];
        outb[(size_t)b * FEATDIM + qp * NQ + tid] = s / sumv;
    }
}

// ---- Kernel: classifier -----------------------------------------------------
__global__ __launch_bounds__(256) void cls_kernel(
    const float* __restrict__ outb,   // (4,2352)
    const float* __restrict__ Wc,     // (1000,2352)
    const float* __restrict__ bc,     // (1000,)
    float* __restrict__ logits)       // (4,1000)
{
    int o = blockIdx.x, tid = threadIdx.x;
    float acc[NB] = {0.0f, 0.0f, 0.0f, 0.0f};
    const float* wrow = Wc + (size_t)o * FEATDIM;
    for (int j = tid; j < FEATDIM; j += 256) {
        float w = wrow[j];
        #pragma unroll
        for (int b = 0; b < NB; b++) acc[b] += w * outb[(size_t)b * FEATDIM + j];
    }
    #pragma unroll
    for (int b = 0; b < NB; b++) {
        #pragma unroll
        for (int off = 32; off > 0; off >>= 1) acc[b] += __shfl_down(acc[b], off);
    }
    __shared__ float red[4][NB];
    int lane = tid & 63, wv = tid >> 6;
    if (lane == 0) {
        #pragma unroll
        for (int b = 0; b < NB; b++) red[wv][b] = acc[b];
    }
    __syncthreads();
    if (tid < NB) {
        float s = red[0][tid] + red[1][tid] + red[2][tid] + red[3][tid];
        logits[(size_t)tid * NCLS + o] = s + bc[o];
    }
}

// ---- Launch ----------------------------------------------------------------
extern "C" void kernel_launch(void* const* d_in, const int* in_sizes, int n_in,
                              void* d_out, int out_size, void* d_ws, size_t ws_size,
                              hipStream_t stream) {
    const float* x     = (const float*)d_in[0];
    const float* Wp    = (const float*)d_in[1];
    const float* bproj = (const float*)d_in[2];
    const float* qp    = (const float*)d_in[3];
    const float* kp    = (const float*)d_in[4];
    const float* vp    = (const float*)d_in[5];
    const float* Wc    = (const float*)d_in[6];
    const float* bc    = (const float*)d_in[7];
    float* logits = (float*)d_out;

    float* ws   = (float*)d_ws;
    float* qkv  = ws;                 // 3*784*12 = 28224 floats
    float* outb = ws + 28224;         // 4*2352   =  9408 floats

    qcirc_kernel<<<dim3(NPATCH, NB, 3), 256, 0, stream>>>(x, Wp, bproj, qp, kp, vp, qkv);
    attn_kernel <<<dim3(NPATCH, NB),    256, 0, stream>>>(qkv, outb);
    cls_kernel  <<<NCLS,                256, 0, stream>>>(outb, Wc, bc, logits);
}